// Round 10
// baseline (436.499 us; speedup 1.0000x reference)
//
#include <hip/hip_runtime.h>
#include <math.h>

// NeuralMemory on MI355X — R17: barrier-free wgemm, W direct from L1/L2.
// R16 post-mortem: global_load_lds staging neutral (252 vs 248) -> W staging
// never was the bottleneck; the W-fill __syncthreads (full vmcnt drain for
// all 8 waves) + 78KB LDS was. R17 deletes the Ws tile: W-frags are loaded
// straight from global per nt-subtile (16 rows x 512B = 8KB, L1-resident;
// all 8 waves of a block share the same 64KB half-tile). EPI 1/3/4 have NO
// barriers; EPI 2/5 keep two cheap ones (accsh zero at entry, pre-flush).
// LDS 78KB -> 13KB. Accumulation order per acc[nt] unchanged -> bit-identical.
// Producers/rgemm/gradstep/prep_w are R13-exact (linear wt layout).

#define NTOK 32768
#define NM ((size_t)NTOK * 256)
#define LRc 1e-3f
#define WDc 1e-2f
#define EPSc 1e-8f

typedef __attribute__((ext_vector_type(8))) short bf16x8;
typedef __attribute__((ext_vector_type(4))) float f32x4;

__device__ __forceinline__ float b2f(unsigned short u) {
    union { unsigned int i; float f; } c;
    c.i = ((unsigned int)u) << 16;
    return c.f;
}
__device__ __forceinline__ unsigned short f2b(float f) {
    union { float f; unsigned int i; } c;
    c.f = f;
    unsigned int i = c.i;
    return (unsigned short)((i + 0x7FFFu + ((i >> 16) & 1u)) >> 16);
}
__device__ __forceinline__ float sigm(float z) { return 1.f / (1.f + __expf(-z)); }
__device__ __forceinline__ float siluf(float z) { return z * sigm(z); }
__device__ __forceinline__ float dsiluf(float z) {
    float s = sigm(z);
    return s * (1.f + z * (1.f - s));
}
__device__ __forceinline__ void unpack4(uint2 u, float* f) {
    f[0] = b2f(u.x & 0xFFFF); f[1] = b2f(u.x >> 16);
    f[2] = b2f(u.y & 0xFFFF); f[3] = b2f(u.y >> 16);
}
__device__ __forceinline__ uint2 pack4(const float* f) {
    uint2 o;
    o.x = (unsigned)f2b(f[0]) | ((unsigned)f2b(f[1]) << 16);
    o.y = (unsigned)f2b(f[2]) | ((unsigned)f2b(f[3]) << 16);
    return o;
}

#define SSTR 40    // scratch row stride in shorts (80 B, 16B-aligned)

// per-nt MFMA sub-block: 8 W-frag loads off one base (imm offsets) + 8 MFMAs
#define MFMA_NT(WBASE, FR)                                                  \
    {                                                                       \
        _Pragma("unroll") for (int nt_ = 0; nt_ < 8; nt_++) {               \
            const unsigned short* wp_ =                                     \
                (WBASE) + (size_t)(nt_ * 16 + cc) * 256 + q * 8;            \
            bf16x8 wf_[8];                                                  \
            _Pragma("unroll") for (int c_ = 0; c_ < 8; c_++)                \
                wf_[c_] = *(const bf16x8*)(wp_ + c_ * 32);                  \
            _Pragma("unroll") for (int c_ = 0; c_ < 8; c_++)                \
                acc[nt_] = __builtin_amdgcn_mfma_f32_16x16x32_bf16(         \
                    wf_[c_], (FR)[c_], acc[nt_], 0, 0, 0);                  \
        }                                                                   \
    }

// ---------------------------------------------------------------------------
// Projections: K,Q,V = X @ {Wk,Wq,Wv}, z-loop inside block, barrier-free
// after the Ls fill. Reads x fp32 (converts in-register) + computes alr.
// ---------------------------------------------------------------------------
__global__ __launch_bounds__(512, 4) void wgemm3_k(
    const float* __restrict__ x, const float* __restrict__ Wlr,
    const float* __restrict__ blr, const unsigned short* __restrict__ wt,
    unsigned short* __restrict__ Kb, unsigned short* __restrict__ Qb,
    unsigned short* __restrict__ Vb, float* __restrict__ alr) {
    __shared__ __attribute__((aligned(16))) unsigned short Sc[8][16 * SSTR];
    __shared__ float Ls[256];
    const int n0 = blockIdx.x * 128, m0 = blockIdx.y * 128;
    const int tid = threadIdx.x, lane = tid & 63, wv = tid >> 6;
    const int cc = lane & 15, q = lane >> 4;
    const int t0 = m0 + wv * 16, tok = t0 + cc;

    if (tid < 256) Ls[tid] = Wlr[tid];
    __syncthreads();  // only barrier in the kernel (nothing in flight yet)

    // ---- X-frag load (fp32) + convert + alr partial dot
    const float* xp = x + (size_t)tok * 256 + q * 8;
    bf16x8 xf[8];
    float s = 0.f;
#pragma unroll
    for (int c = 0; c < 8; c++) {
        float xv[8];
        *(float4*)&xv[0] = *(const float4*)(xp + c * 32);
        *(float4*)&xv[4] = *(const float4*)(xp + c * 32 + 4);
        float wl[8];
        *(float4*)&wl[0] = *(const float4*)&Ls[c * 32 + q * 8];
        *(float4*)&wl[4] = *(const float4*)&Ls[c * 32 + q * 8 + 4];
        unsigned short us[8];
#pragma unroll
        for (int j = 0; j < 8; j++) {
            s += xv[j] * wl[j];
            us[j] = f2b(xv[j]);
        }
        xf[c] = *(bf16x8*)us;
    }
    s += __shfl_xor(s, 16);
    s += __shfl_xor(s, 32);
    if (n0 == 0 && q == 0) alr[tok] = 0.1f * sigm(s + blr[0]);

    unsigned short* sc = &Sc[wv][0];
    const int rtok = lane >> 2, roct = (lane & 3) * 8;
    unsigned short* const outs[3] = {Kb, Qb, Vb};

    for (int z = 0; z < 3; z++) {
        const unsigned short* Wb = wt + (size_t)z * 65536 + (size_t)n0 * 256;
        f32x4 acc[8];
#pragma unroll
        for (int t = 0; t < 8; t++) acc[t] = (f32x4){0.f, 0.f, 0.f, 0.f};
        MFMA_NT(Wb, xf);

        unsigned short* Cb = outs[z];
#pragma unroll
        for (int pr = 0; pr < 4; pr++) {
#pragma unroll
            for (int h = 0; h < 2; h++) {
                const int nt = pr * 2 + h;
                f32x4 c4 = acc[nt];
                float o[4] = {c4[0], c4[1], c4[2], c4[3]};
                *(uint2*)&sc[cc * SSTR + h * 16 + q * 4] = pack4(o);
            }
            uint4 pk = *(const uint4*)&sc[rtok * SSTR + roct];
            *(uint4*)(Cb + (size_t)(t0 + rtok) * 256 + n0 + pr * 32 + roct) = pk;
        }
    }
}

// ---------------------------------------------------------------------------
// Operand-swapped tall GEMM: C[M,256] = X[M,256] @ B with Bt[n][k]=B[k][n].
// EPI 1: z=acc+bias; Zout=z; Cb = X+silu(z)           fwd layer 0
// EPI 5: z=acc+bias; h2=X+silu(z); dh=alr'* (h2-V);   fwd layer 1 + bwd elem
//        dz=dh*dsilu(z); Cb=dz; Rout=dh; colsum(dz)->gB
// EPI 2: dz0=(acc+Rin)*dsilu(Zin); Cb=dz0; colsum->gB bwd layer 0
// EPI 3: Cb = X + silu(acc+bias)                      retrieved L0
// EPI 4: Cf = X + silu(acc+bias)  (fp32 out)          retrieved L1
// R17: no Ws tile; EPI 1/3/4 barrier-free; EPI 2/5 barrier only at entry
// (accsh zero, nothing in flight) and pre-flush.
// ---------------------------------------------------------------------------
template <int EPI>
__global__ __launch_bounds__(512, 4) void wgemm_k(
    const unsigned short* __restrict__ A, const unsigned short* __restrict__ Bt,
    const float* __restrict__ bias, const unsigned short* __restrict__ Rin,
    const unsigned short* __restrict__ Zin, const unsigned short* __restrict__ Vb,
    const float* __restrict__ alr, float* __restrict__ gB,
    unsigned short* __restrict__ Cb, float* __restrict__ Cf,
    unsigned short* __restrict__ Zout, unsigned short* __restrict__ Rout) {
    __shared__ __attribute__((aligned(16))) unsigned short Sc[8][16 * SSTR];
    __shared__ float accsh[128];
    const int n0 = blockIdx.x * 128, m0 = blockIdx.y * 128;
    const int tid = threadIdx.x, lane = tid & 63, wv = tid >> 6;
    const int cc = lane & 15, q = lane >> 4;
    const int t0 = m0 + wv * 16, tok = t0 + cc;

    if (EPI == 2 || EPI == 5) {
        if (tid < 128) accsh[tid] = 0.f;
        __syncthreads();  // entry barrier: nothing in flight yet
    }

    // ---- X-frag loads: 8 instrs off one base (imm offsets)
    const unsigned short* xp = A + (size_t)tok * 256 + q * 8;
    bf16x8 xf[8];
#pragma unroll
    for (int c = 0; c < 8; c++) xf[c] = *(const bf16x8*)(xp + c * 32);

    f32x4 acc[8];
#pragma unroll
    for (int t = 0; t < 8; t++) acc[t] = (f32x4){0.f, 0.f, 0.f, 0.f};
    MFMA_NT(Bt + (size_t)n0 * 256, xf);

    // ---- epilogue: lane holds token tok, cols nt*16 + 4q + r (r=0..3)
    float lalr = 0.f;
    if (EPI == 5) lalr = alr[tok] * (2.f / 256.f);
    unsigned short* sc = &Sc[wv][0];
    const int rtok = lane >> 2, roct = (lane & 3) * 8;  // repack read indices

#pragma unroll
    for (int pr = 0; pr < 4; pr++) {  // tile pairs (2pr, 2pr+1) = 32 cols
        float o2[2][4], z2[2][4];     // primary / secondary quad outputs
#pragma unroll
        for (int h = 0; h < 2; h++) {
            const int nt = pr * 2 + h;
            const int gcol = n0 + nt * 16 + q * 4;
            const size_t off = (size_t)tok * 256 + gcol;
            f32x4 c = acc[nt];
            float v[4] = {c[0], c[1], c[2], c[3]};
            if (EPI == 1) {
                float bv[4], a[4];
                *(float4*)bv = *(const float4*)(bias + gcol);
                unpack4(*(const uint2*)(A + off), a);
#pragma unroll
                for (int r = 0; r < 4; r++) {
                    float z = v[r] + bv[r];
                    z2[h][r] = z;
                    o2[h][r] = a[r] + siluf(z);
                }
            } else if (EPI == 5) {
                float bv[4], a[4], vv[4];
                *(float4*)bv = *(const float4*)(bias + gcol);
                unpack4(*(const uint2*)(A + off), a);
                unpack4(*(const uint2*)(Vb + off), vv);
#pragma unroll
                for (int r = 0; r < 4; r++) {
                    float z = v[r] + bv[r];
                    float h2 = a[r] + siluf(z);
                    float dh = lalr * (h2 - vv[r]);
                    o2[h][r] = dh * dsiluf(z);  // dz
                    z2[h][r] = dh;              // dh
                }
            } else if (EPI == 2) {
                float ri[4], zi[4];
                unpack4(*(const uint2*)(Rin + off), ri);
                unpack4(*(const uint2*)(Zin + off), zi);
#pragma unroll
                for (int r = 0; r < 4; r++)
                    o2[h][r] = (v[r] + ri[r]) * dsiluf(zi[r]);
            } else {  // EPI 3 / 4
                float bv[4], a[4];
                *(float4*)bv = *(const float4*)(bias + gcol);
                unpack4(*(const uint2*)(A + off), a);
#pragma unroll
                for (int r = 0; r < 4; r++) o2[h][r] = a[r] + siluf(v[r] + bv[r]);
            }
            if (EPI == 4) {  // fp32 direct store: 4 lanes x 16 B = 64 B segs
                *(float4*)(Cf + off) = *(float4*)o2[h];
            }
            if (EPI == 2 || EPI == 5) {  // fused bias-grad column sums of dz
                float s0 = o2[h][0], s1 = o2[h][1], s2 = o2[h][2], s3 = o2[h][3];
#pragma unroll
                for (int m = 1; m < 16; m <<= 1) {
                    s0 += __shfl_xor(s0, m);
                    s1 += __shfl_xor(s1, m);
                    s2 += __shfl_xor(s2, m);
                    s3 += __shfl_xor(s3, m);
                }
                if (cc == 0) {
                    const int lc = nt * 16 + q * 4;
                    atomicAdd(&accsh[lc], s0);
                    atomicAdd(&accsh[lc + 1], s1);
                    atomicAdd(&accsh[lc + 2], s2);
                    atomicAdd(&accsh[lc + 3], s3);
                }
            }
        }
        if (EPI == 4) continue;
        // repack via wave-private scratch -> 64 B segment stores
#pragma unroll
        for (int h = 0; h < 2; h++)
            *(uint2*)&sc[cc * SSTR + h * 16 + q * 4] = pack4(o2[h]);
        uint4 pk = *(const uint4*)&sc[rtok * SSTR + roct];
        *(uint4*)(Cb + (size_t)(t0 + rtok) * 256 + n0 + pr * 32 + roct) = pk;
        if (EPI == 1 || EPI == 5) {  // second output (Zout / Rout)
#pragma unroll
            for (int h = 0; h < 2; h++)
                *(uint2*)&sc[cc * SSTR + h * 16 + q * 4] = pack4(z2[h]);
            uint4 pk2 = *(const uint4*)&sc[rtok * SSTR + roct];
            unsigned short* P2 = (EPI == 1) ? Zout : Rout;
            *(uint4*)(P2 + (size_t)(t0 + rtok) * 256 + n0 + pr * 32 + roct) = pk2;
        }
    }
    if (EPI == 2 || EPI == 5) {  // flush block-local col sums
        __syncthreads();
        if (tid < 128) atomicAdd(&gB[n0 + tid], accsh[tid]);
    }
}

// ---------------------------------------------------------------------------
// Reduction GEMM (weight grads): C[i][j] = sum_t A[t][i] B[t][j], split-K 32.
// Conflict-free swizzled transpose staging + prefetch + 8 waves/block (R9).
// ---------------------------------------------------------------------------
__global__ __launch_bounds__(512, 4) void rgemm_k(
    const unsigned short* __restrict__ Kb, const unsigned short* __restrict__ h1b,
    const unsigned short* __restrict__ dz0b,
    const unsigned short* __restrict__ dz1b, float* __restrict__ pbuf) {
    __shared__ unsigned short As[128 * 64];
    __shared__ unsigned short Bs2[128 * 64];
    const int z = blockIdx.z, layer = z >> 5, zc = z & 31;
    const unsigned short* Ag = layer ? h1b : Kb;
    const unsigned short* Bg = layer ? dz1b : dz0b;
    const int t0 = zc * 1024;
    const int j0 = blockIdx.x * 128, i0 = blockIdx.y * 128;
    const int tid = threadIdx.x, lane = tid & 63, wave = tid >> 6;

    // staging role: threads 0-255 stage A, 256-511 stage B
    const int half = tid >> 8;
    const int t9 = tid & 255;
    const int ptq = t9 >> 4;          // token pair 0..15
    const int pi = (t9 & 15) * 8;     // col group base
    const unsigned short* sg = half ? Bg : Ag;
    const int nb = half ? j0 : i0;
    unsigned int* dst = (unsigned int*)(half ? Bs2 : As);
    const unsigned short* gp = sg + (size_t)(t0 + ptq * 2) * 256 + nb + pi;

    // wave output tile: 64 rows (i) x 32 cols (j)
    const int wr = (wave >> 2) * 64, wc = (wave & 3) * 32;
    const int fr = lane & 15, fkb = lane >> 4;

    f32x4 acc[4][2];
#pragma unroll
    for (int i = 0; i < 4; i++)
#pragma unroll
        for (int j = 0; j < 2; j++) acc[i][j] = (f32x4){0.f, 0.f, 0.f, 0.f};

    uint4 u0 = *(const uint4*)gp;
    uint4 u1 = *(const uint4*)(gp + 256);
    gp += 32 * 256;

    for (int it = 0; it < 32; it++) {
        // transpose-write: pack (token 2q, 2q+1) per col, swizzled slot
        const unsigned int* w0 = (const unsigned int*)&u0;
        const unsigned int* w1 = (const unsigned int*)&u1;
#pragma unroll
        for (int ii = 0; ii < 8; ii++) {
            unsigned int lo = (w0[ii >> 1] >> (16 * (ii & 1))) & 0xFFFFu;
            unsigned int hi = (w1[ii >> 1] >> (16 * (ii & 1))) & 0xFFFFu;
            const int col = pi + ii;
            const int s2 = ((col >> 3) ^ col) & 3;
            const int s4 = ((col >> 2) ^ (col >> 5)) & 1;
            dst[col * 32 + (ptq ^ (s2 << 2) ^ (s4 << 4))] = lo | (hi << 16);
        }
        __syncthreads();
        if (it < 31) {  // prefetch next K-chunk; latency hides under MFMA phase
            u0 = *(const uint4*)gp;
            u1 = *(const uint4*)(gp + 256);
            gp += 32 * 256;
        }
        bf16x8 af[4], bfr[2];
#pragma unroll
        for (int i = 0; i < 4; i++) {
            const int col = wr + i * 16 + fr;
            const int s2 = ((col >> 3) ^ col) & 3;
            const int s4 = ((col >> 2) ^ (col >> 5)) & 1;
            af[i] = *(const bf16x8*)&As[col * 64 + (fkb ^ s2 ^ (s4 << 2)) * 8];
        }
#pragma unroll
        for (int j = 0; j < 2; j++) {
            const int col = wc + j * 16 + fr;
            const int s2 = ((col >> 3) ^ col) & 3;
            const int s4 = ((col >> 2) ^ (col >> 5)) & 1;
            bfr[j] = *(const bf16x8*)&Bs2[col * 64 + (fkb ^ s2 ^ (s4 << 2)) * 8];
        }
#pragma unroll
        for (int i = 0; i < 4; i++)
#pragma unroll
            for (int j = 0; j < 2; j++)
                acc[i][j] = __builtin_amdgcn_mfma_f32_16x16x32_bf16(
                    af[i], bfr[j], acc[i][j], 0, 0, 0);
        __syncthreads();
    }

    float* P = pbuf + (size_t)((layer << 5) + zc) * 65536;
    const int r0 = fkb * 4;
#pragma unroll
    for (int mi = 0; mi < 4; mi++)
#pragma unroll
        for (int ni = 0; ni < 2; ni++) {
            f32x4 c = acc[mi][ni];
#pragma unroll
            for (int r = 0; r < 4; r++)
                P[(size_t)(i0 + wr + mi * 16 + r0 + r) * 256 +
                  (j0 + wc + ni * 16 + fr)] = c[r];
        }
}

// ---------------------------------------------------------------------------
// gradstep: reduce pbuf (32 chunks) -> g; surprises; AdamW for W and b.
// blocks 0..511: weights (256 threads each). block 512: biases.
// ---------------------------------------------------------------------------
__global__ __launch_bounds__(256) void gradstep_k(
    const float* __restrict__ pbuf, const float* __restrict__ Ws,
    const float* __restrict__ bs, const float* __restrict__ accB,
    unsigned short* __restrict__ nWt, float* __restrict__ nb,
    float* __restrict__ outSW, float* __restrict__ outSb) {
    const int bi = blockIdx.x;
    if (bi < 512) {
        const int idx = bi * 256 + threadIdx.x;  // 0..131071
        const int layer = idx >> 16, rc = idx & 65535;
        const float* p = pbuf + (size_t)layer * 32 * 65536 + rc;
        float g = 0.f;
#pragma unroll 8
        for (int c = 0; c < 32; c++) g += p[(size_t)c * 65536];
        outSW[idx] = -g;
        float nw = Ws[idx] * (1.f - LRc * WDc) - LRc * g / (fabsf(g) + EPSc);
        const int l = idx >> 16, k = (idx >> 8) & 255, n = idx & 255;
        nWt[(size_t)l * 65536 + n * 256 + k] = f2b(nw);
    } else {
        for (int i = threadIdx.x; i < 512; i += 256) {
            float g = accB[i];
            outSb[i] = -g;
            nb[i] = bs[i] * (1.f - LRc * WDc) - LRc * g / (fabsf(g) + EPSc);
        }
    }
}

// ---------------------------------------------------------------------------
// prep_w: blocks 0..1535 -> weight transpose+cvt (z=0..4) / cvt (z=5)
//         block 1536     -> zero accB[512]
// ---------------------------------------------------------------------------
__global__ __launch_bounds__(256) void prep_w_k(
    const float* __restrict__ Wk, const float* __restrict__ Wq,
    const float* __restrict__ Wv, const float* __restrict__ Ws,
    unsigned short* __restrict__ wt, float* __restrict__ accB) {
    const int bi = blockIdx.x;
    if (bi < 1536) {
        const int z = bi >> 8;
        const int idx = (bi & 255) * 256 + threadIdx.x;  // 0..65535
        const float* src = z == 0 ? Wk : z == 1 ? Wq : z == 2 ? Wv
                         : z == 3 ? Ws : Ws + 65536;
        unsigned short* dst = wt + (size_t)z * 65536;
        float v = src[idx];
        if (z == 5)
            dst[idx] = f2b(v);
        else
            dst[(idx & 255) * 256 + (idx >> 8)] = f2b(v);
    } else {
        accB[threadIdx.x] = 0.f;
        accB[threadIdx.x + 256] = 0.f;
    }
}

extern "C" void kernel_launch(void* const* d_in, const int* in_sizes, int n_in,
                              void* d_out, int out_size, void* d_ws,
                              size_t ws_size, hipStream_t stream) {
    const float* x = (const float*)d_in[0];
    const float* Wk = (const float*)d_in[1];
    const float* Wq = (const float*)d_in[2];
    const float* Wv = (const float*)d_in[3];
    const float* Wlr = (const float*)d_in[4];
    const float* blr = (const float*)d_in[5];
    const float* Ws = (const float*)d_in[6];
    const float* bs = (const float*)d_in[7];

    unsigned short* S = (unsigned short*)d_ws;
    unsigned short* xb = S + 0 * NM;  // r1b scratch (retrieval intermediate)
    unsigned short* Kb = S + 1 * NM;
    unsigned short* Qb = S + 2 * NM;
    unsigned short* Vb = S + 3 * NM;
    unsigned short* z0b = S + 4 * NM;
    unsigned short* h1b = S + 5 * NM;
    unsigned short* dz1b = S + 6 * NM;
    unsigned short* dh2b = S + 7 * NM;
    unsigned short* dz0b = S + 8 * NM;
    float* pbuf = (float*)(S + 9 * NM);  // 16 MB (slot 9): 2 layers x 32 chunks
    unsigned short* r1b = xb;

    unsigned short* wt = S + 11 * NM;
    unsigned short* W0t = wt + 3 * 65536;
    unsigned short* W1t = wt + 4 * 65536;
    unsigned short* W1b = wt + 5 * 65536;
    unsigned short* nW0t = wt + 6 * 65536;
    unsigned short* nW1t = wt + 7 * 65536;
    float* ft = (float*)(wt + 8 * 65536);
    float* alr = ft;              // 32768
    float* accB = ft + 32768;     // 512
    float* nb = accB + 512;       // 512

    float* out_ret = (float*)d_out;
    float* out_sW = out_ret + NM;
    float* out_sb = out_sW + 131072;

    dim3 blk5(512);
    dim3 blk(256);
    dim3 g_tall(2, 256);

    // prep: weight transpose/cvt + zero accB (x handled inside wgemm3_k)
    prep_w_k<<<1537, blk, 0, stream>>>(Wk, Wq, Wv, Ws, wt, accB);

    // projections K,Q,V (+ x->bf16 conversion + alr), z-loop inside block
    wgemm3_k<<<g_tall, blk5, 0, stream>>>(x, Wlr, blr, wt, Kb, Qb, Vb, alr);

    // fwd layer 0: h1 = K + silu(K@W0 + b0); saves z0
    wgemm_k<1><<<g_tall, blk5, 0, stream>>>(Kb, W0t, bs, nullptr, nullptr,
                                            nullptr, nullptr, nullptr, h1b,
                                            nullptr, z0b, nullptr);

    // fwd layer 1 + bwd elementwise: dz1, dh2 (+ colsum dz1 -> accB[256..])
    wgemm_k<5><<<g_tall, blk5, 0, stream>>>(h1b, W1t, bs + 256, nullptr,
                                            nullptr, Vb, alr, accB + 256,
                                            dz1b, nullptr, nullptr, dh2b);

    // bwd layer 0: dz0 = (dz1@W1^T + dh2) * dsilu(z0) (+ colsum -> accB[0..])
    wgemm_k<2><<<g_tall, blk5, 0, stream>>>(dz1b, W1b, nullptr, dh2b, z0b,
                                            nullptr, nullptr, accB, dz0b,
                                            nullptr, nullptr, nullptr);

    // weight grads: swizzled transpose-on-load split-K partials
    rgemm_k<<<dim3(2, 2, 64), blk5, 0, stream>>>(Kb, h1b, dz0b, dz1b, pbuf);

    // reduce + surprises + AdamW (W and b) in one dispatch
    gradstep_k<<<513, blk, 0, stream>>>(pbuf, Ws, bs, accB, nW0t, nb, out_sW,
                                        out_sb);

    // retrieved with new weights (two tall passes)
    wgemm_k<3><<<g_tall, blk5, 0, stream>>>(Qb, nW0t, nb, nullptr, nullptr,
                                            nullptr, nullptr, nullptr, r1b,
                                            nullptr, nullptr, nullptr);
    wgemm_k<4><<<g_tall, blk5, 0, stream>>>(r1b, nW1t, nb + 256, nullptr,
                                            nullptr, nullptr, nullptr, nullptr,
                                            nullptr, out_ret, nullptr, nullptr);
}

// Round 11
// 247.140 us; speedup vs baseline: 1.7662x; 1.7662x over previous
//
#include <hip/hip_runtime.h>
#include <math.h>

// NeuralMemory on MI355X — R18: R13-exact base + T1 XCD-aware block swizzle.
// R17 post-mortem: direct-from-global W (no LDS tile) = 16-line gathers with
// per-nt vmcnt chains per wave -> 436 us. REVERTED. R13 (247.3/247.7 us,
// verified twice) is the anchor. R18's single zero-risk change: tall passes
// use a flattened 1D grid (512, 512%8==0 -> simple bijective swizzle) with
// sw=(id&7)*64+(id>>3), so both n-halves of a token group + 32 adjacent
// groups land on ONE XCD -> X/residual reads hit that XCD's L2 instead of
// bouncing through L3. Pure index remap; bit-identical math.

#define NTOK 32768
#define NM ((size_t)NTOK * 256)
#define LRc 1e-3f
#define WDc 1e-2f
#define EPSc 1e-8f

typedef __attribute__((ext_vector_type(8))) short bf16x8;
typedef __attribute__((ext_vector_type(4))) float f32x4;

__device__ __forceinline__ float b2f(unsigned short u) {
    union { unsigned int i; float f; } c;
    c.i = ((unsigned int)u) << 16;
    return c.f;
}
__device__ __forceinline__ unsigned short f2b(float f) {
    union { float f; unsigned int i; } c;
    c.f = f;
    unsigned int i = c.i;
    return (unsigned short)((i + 0x7FFFu + ((i >> 16) & 1u)) >> 16);
}
__device__ __forceinline__ float sigm(float z) { return 1.f / (1.f + __expf(-z)); }
__device__ __forceinline__ float siluf(float z) { return z * sigm(z); }
__device__ __forceinline__ float dsiluf(float z) {
    float s = sigm(z);
    return s * (1.f + z * (1.f - s));
}
__device__ __forceinline__ void unpack4(uint2 u, float* f) {
    f[0] = b2f(u.x & 0xFFFF); f[1] = b2f(u.x >> 16);
    f[2] = b2f(u.y & 0xFFFF); f[3] = b2f(u.y >> 16);
}
__device__ __forceinline__ uint2 pack4(const float* f) {
    uint2 o;
    o.x = (unsigned)f2b(f[0]) | ((unsigned)f2b(f[1]) << 16);
    o.y = (unsigned)f2b(f[2]) | ((unsigned)f2b(f[3]) << 16);
    return o;
}

#define WSTR 264   // W tile row stride in shorts (33x 16B units, odd => rotate)
#define SSTR 40    // scratch row stride in shorts (80 B, 16B-aligned)

// XCD-aware swizzle for the 512-block tall passes (512 % 8 == 0 -> bijective):
// blocks on XCD j (id%8==j) cover contiguous sw in [j*64,(j+1)*64) -> both
// n-halves + 32 adjacent token groups share one XCD's L2.
__device__ __forceinline__ void tall_coords(int id, int& n0, int& m0) {
    const int sw = (id & 7) * 64 + (id >> 3);
    n0 = (sw & 1) * 128;
    m0 = (sw >> 1) * 128;
}

// ---------------------------------------------------------------------------
// Projections: K,Q,V = X @ {Wk,Wq,Wv} in one kernel, z-loop inside block.
// Reads x fp32 directly (frag-shaped), converts in-register, computes alr
// from LDS-resident Wlr (n0==0 blocks write).
// ---------------------------------------------------------------------------
__global__ __launch_bounds__(512, 4) void wgemm3_k(
    const float* __restrict__ x, const float* __restrict__ Wlr,
    const float* __restrict__ blr, const unsigned short* __restrict__ wt,
    unsigned short* __restrict__ Kb, unsigned short* __restrict__ Qb,
    unsigned short* __restrict__ Vb, float* __restrict__ alr) {
    __shared__ unsigned short Ws[128 * WSTR];
    __shared__ unsigned short Sc[8][16 * SSTR];
    __shared__ float Ls[256];
    int n0, m0;
    tall_coords(blockIdx.x, n0, m0);
    const int tid = threadIdx.x, lane = tid & 63, wv = tid >> 6;
    const int cc = lane & 15, q = lane >> 4;
    const int t0 = m0 + wv * 16, tok = t0 + cc;

    if (tid < 256) Ls[tid] = Wlr[tid];
    __syncthreads();  // Ls ready before the dot below

    // ---- X-frag load (fp32) + convert + alr partial dot
    const float* xp = x + (size_t)tok * 256 + q * 8;
    bf16x8 xf[8];
    float s = 0.f;
#pragma unroll
    for (int c = 0; c < 8; c++) {
        float xv[8];
        *(float4*)&xv[0] = *(const float4*)(xp + c * 32);
        *(float4*)&xv[4] = *(const float4*)(xp + c * 32 + 4);
        float wl[8];
        *(float4*)&wl[0] = *(const float4*)&Ls[c * 32 + q * 8];
        *(float4*)&wl[4] = *(const float4*)&Ls[c * 32 + q * 8 + 4];
        unsigned short us[8];
#pragma unroll
        for (int j = 0; j < 8; j++) {
            s += xv[j] * wl[j];
            us[j] = f2b(xv[j]);
        }
        xf[c] = *(bf16x8*)us;
    }
    s += __shfl_xor(s, 16);
    s += __shfl_xor(s, 32);
    if (n0 == 0 && q == 0) alr[tok] = 0.1f * sigm(s + blr[0]);

    unsigned short* sc = &Sc[wv][0];
    const int rtok = lane >> 2, roct = (lane & 3) * 8;
    unsigned short* const outs[3] = {Kb, Qb, Vb};

    for (int z = 0; z < 3; z++) {
        __syncthreads();  // prior z's Ws reads complete before refill
#pragma unroll
        for (int it = 0; it < 8; it++) {
            int i = it * 512 + tid;
            int row = i >> 5, g8 = i & 31;
            *(uint4*)&Ws[row * WSTR + g8 * 8] =
                *(const uint4*)(wt + (size_t)z * 65536 +
                                (size_t)(n0 + row) * 256 + g8 * 8);
        }
        __syncthreads();

        f32x4 acc[8];
#pragma unroll
        for (int t = 0; t < 8; t++) acc[t] = (f32x4){0.f, 0.f, 0.f, 0.f};
#pragma unroll
        for (int c = 0; c < 8; c++) {
#pragma unroll
            for (int nt = 0; nt < 8; nt++) {
                bf16x8 wf =
                    *(const bf16x8*)&Ws[(nt * 16 + cc) * WSTR + c * 32 + q * 8];
                acc[nt] = __builtin_amdgcn_mfma_f32_16x16x32_bf16(wf, xf[c],
                                                                  acc[nt], 0, 0, 0);
            }
        }

        unsigned short* Cb = outs[z];
#pragma unroll
        for (int pr = 0; pr < 4; pr++) {
#pragma unroll
            for (int h = 0; h < 2; h++) {
                const int nt = pr * 2 + h;
                f32x4 c4 = acc[nt];
                float o[4] = {c4[0], c4[1], c4[2], c4[3]};
                *(uint2*)&sc[cc * SSTR + h * 16 + q * 4] = pack4(o);
            }
            uint4 pk = *(const uint4*)&sc[rtok * SSTR + roct];
            *(uint4*)(Cb + (size_t)(t0 + rtok) * 256 + n0 + pr * 32 + roct) = pk;
        }
    }
}

// ---------------------------------------------------------------------------
// Operand-swapped tall GEMM: C[M,256] = X[M,256] @ B with Bt[n][k]=B[k][n].
// EPI 1: z=acc+bias; Zout=z; Cb = X+silu(z)           fwd layer 0
// EPI 5: z=acc+bias; h2=X+silu(z); dh=alr'* (h2-V);   fwd layer 1 + bwd elem
//        dz=dh*dsilu(z); Cb=dz; Rout=dh; colsum(dz)->gB
// EPI 2: dz0=(acc+Rin)*dsilu(Zin); Cb=dz0; colsum->gB bwd layer 0
// EPI 3: Cb = X + silu(acc+bias)                      retrieved L0
// EPI 4: Cf = X + silu(acc+bias)  (fp32 out)          retrieved L1
// ---------------------------------------------------------------------------
template <int EPI>
__global__ __launch_bounds__(512, 4) void wgemm_k(
    const unsigned short* __restrict__ A, const unsigned short* __restrict__ Bt,
    const float* __restrict__ bias, const unsigned short* __restrict__ Rin,
    const unsigned short* __restrict__ Zin, const unsigned short* __restrict__ Vb,
    const float* __restrict__ alr, float* __restrict__ gB,
    unsigned short* __restrict__ Cb, float* __restrict__ Cf,
    unsigned short* __restrict__ Zout, unsigned short* __restrict__ Rout) {
    __shared__ unsigned short Ws[128 * WSTR];
    __shared__ unsigned short Sc[8][16 * SSTR];
    __shared__ float accsh[128];
    int n0, m0;
    tall_coords(blockIdx.x, n0, m0);
    const int tid = threadIdx.x, lane = tid & 63, wv = tid >> 6;
    const int cc = lane & 15, q = lane >> 4;

    // ---- X-frag loads: 8 instrs off one base (imm offsets)
    const int t0 = m0 + wv * 16;
    const unsigned short* xp = A + (size_t)(t0 + cc) * 256 + q * 8;
    bf16x8 xf[8];
#pragma unroll
    for (int c = 0; c < 8; c++) xf[c] = *(const bf16x8*)(xp + c * 32);

    if (EPI == 2 || EPI == 5) {
        if (tid < 128) accsh[tid] = 0.f;
    }

    // ---- W half-tile fill: [128 n-rows][256 k] shorts, padded stride
#pragma unroll
    for (int it = 0; it < 8; it++) {
        int i = it * 512 + tid;
        int row = i >> 5, g8 = i & 31;
        *(uint4*)&Ws[row * WSTR + g8 * 8] =
            *(const uint4*)(Bt + (size_t)(n0 + row) * 256 + g8 * 8);
    }
    __syncthreads();

    f32x4 acc[8];
#pragma unroll
    for (int t = 0; t < 8; t++) acc[t] = (f32x4){0.f, 0.f, 0.f, 0.f};

#pragma unroll
    for (int c = 0; c < 8; c++) {
#pragma unroll
        for (int nt = 0; nt < 8; nt++) {
            bf16x8 wf = *(const bf16x8*)&Ws[(nt * 16 + cc) * WSTR + c * 32 + q * 8];
            acc[nt] = __builtin_amdgcn_mfma_f32_16x16x32_bf16(wf, xf[c],
                                                              acc[nt], 0, 0, 0);
        }
    }

    // ---- epilogue: lane holds token t0+cc, cols nt*16 + 4q + r (r=0..3)
    const int tok = t0 + cc;
    float lalr = 0.f;
    if (EPI == 5) lalr = alr[tok] * (2.f / 256.f);
    unsigned short* sc = &Sc[wv][0];
    const int rtok = lane >> 2, roct = (lane & 3) * 8;  // repack read indices

#pragma unroll
    for (int pr = 0; pr < 4; pr++) {  // tile pairs (2pr, 2pr+1) = 32 cols
        float o2[2][4], z2[2][4];     // primary / secondary quad outputs
#pragma unroll
        for (int h = 0; h < 2; h++) {
            const int nt = pr * 2 + h;
            const int gcol = n0 + nt * 16 + q * 4;
            const size_t off = (size_t)tok * 256 + gcol;
            f32x4 c = acc[nt];
            float v[4] = {c[0], c[1], c[2], c[3]};
            if (EPI == 1) {
                float bv[4], a[4];
                *(float4*)bv = *(const float4*)(bias + gcol);
                unpack4(*(const uint2*)(A + off), a);
#pragma unroll
                for (int r = 0; r < 4; r++) {
                    float z = v[r] + bv[r];
                    z2[h][r] = z;
                    o2[h][r] = a[r] + siluf(z);
                }
            } else if (EPI == 5) {
                float bv[4], a[4], vv[4];
                *(float4*)bv = *(const float4*)(bias + gcol);
                unpack4(*(const uint2*)(A + off), a);
                unpack4(*(const uint2*)(Vb + off), vv);
#pragma unroll
                for (int r = 0; r < 4; r++) {
                    float z = v[r] + bv[r];
                    float h2 = a[r] + siluf(z);
                    float dh = lalr * (h2 - vv[r]);
                    o2[h][r] = dh * dsiluf(z);  // dz
                    z2[h][r] = dh;              // dh
                }
            } else if (EPI == 2) {
                float ri[4], zi[4];
                unpack4(*(const uint2*)(Rin + off), ri);
                unpack4(*(const uint2*)(Zin + off), zi);
#pragma unroll
                for (int r = 0; r < 4; r++)
                    o2[h][r] = (v[r] + ri[r]) * dsiluf(zi[r]);
            } else {  // EPI 3 / 4
                float bv[4], a[4];
                *(float4*)bv = *(const float4*)(bias + gcol);
                unpack4(*(const uint2*)(A + off), a);
#pragma unroll
                for (int r = 0; r < 4; r++) o2[h][r] = a[r] + siluf(v[r] + bv[r]);
            }
            if (EPI == 4) {  // fp32 direct store: 4 lanes x 16 B = 64 B segs
                *(float4*)(Cf + off) = *(float4*)o2[h];
            }
            if (EPI == 2 || EPI == 5) {  // fused bias-grad column sums of dz
                float s0 = o2[h][0], s1 = o2[h][1], s2 = o2[h][2], s3 = o2[h][3];
#pragma unroll
                for (int m = 1; m < 16; m <<= 1) {
                    s0 += __shfl_xor(s0, m);
                    s1 += __shfl_xor(s1, m);
                    s2 += __shfl_xor(s2, m);
                    s3 += __shfl_xor(s3, m);
                }
                if (cc == 0) {
                    const int lc = nt * 16 + q * 4;
                    atomicAdd(&accsh[lc], s0);
                    atomicAdd(&accsh[lc + 1], s1);
                    atomicAdd(&accsh[lc + 2], s2);
                    atomicAdd(&accsh[lc + 3], s3);
                }
            }
        }
        if (EPI == 4) continue;
        // repack via wave-private scratch -> 64 B segment stores
#pragma unroll
        for (int h = 0; h < 2; h++)
            *(uint2*)&sc[cc * SSTR + h * 16 + q * 4] = pack4(o2[h]);
        uint4 pk = *(const uint4*)&sc[rtok * SSTR + roct];
        *(uint4*)(Cb + (size_t)(t0 + rtok) * 256 + n0 + pr * 32 + roct) = pk;
        if (EPI == 1 || EPI == 5) {  // second output (Zout / Rout)
#pragma unroll
            for (int h = 0; h < 2; h++)
                *(uint2*)&sc[cc * SSTR + h * 16 + q * 4] = pack4(z2[h]);
            uint4 pk2 = *(const uint4*)&sc[rtok * SSTR + roct];
            unsigned short* P2 = (EPI == 1) ? Zout : Rout;
            *(uint4*)(P2 + (size_t)(t0 + rtok) * 256 + n0 + pr * 32 + roct) = pk2;
        }
    }
    if (EPI == 2 || EPI == 5) {  // flush block-local col sums
        __syncthreads();
        if (tid < 128) atomicAdd(&gB[n0 + tid], accsh[tid]);
    }
}

// ---------------------------------------------------------------------------
// Reduction GEMM (weight grads): C[i][j] = sum_t A[t][i] B[t][j], split-K 32.
// Conflict-free swizzled transpose staging + prefetch + 8 waves/block (R9).
// ---------------------------------------------------------------------------
__global__ __launch_bounds__(512, 4) void rgemm_k(
    const unsigned short* __restrict__ Kb, const unsigned short* __restrict__ h1b,
    const unsigned short* __restrict__ dz0b,
    const unsigned short* __restrict__ dz1b, float* __restrict__ pbuf) {
    __shared__ unsigned short As[128 * 64];
    __shared__ unsigned short Bs2[128 * 64];
    const int z = blockIdx.z, layer = z >> 5, zc = z & 31;
    const unsigned short* Ag = layer ? h1b : Kb;
    const unsigned short* Bg = layer ? dz1b : dz0b;
    const int t0 = zc * 1024;
    const int j0 = blockIdx.x * 128, i0 = blockIdx.y * 128;
    const int tid = threadIdx.x, lane = tid & 63, wave = tid >> 6;

    // staging role: threads 0-255 stage A, 256-511 stage B
    const int half = tid >> 8;
    const int t9 = tid & 255;
    const int ptq = t9 >> 4;          // token pair 0..15
    const int pi = (t9 & 15) * 8;     // col group base
    const unsigned short* sg = half ? Bg : Ag;
    const int nb = half ? j0 : i0;
    unsigned int* dst = (unsigned int*)(half ? Bs2 : As);
    const unsigned short* gp = sg + (size_t)(t0 + ptq * 2) * 256 + nb + pi;

    // wave output tile: 64 rows (i) x 32 cols (j)
    const int wr = (wave >> 2) * 64, wc = (wave & 3) * 32;
    const int fr = lane & 15, fkb = lane >> 4;

    f32x4 acc[4][2];
#pragma unroll
    for (int i = 0; i < 4; i++)
#pragma unroll
        for (int j = 0; j < 2; j++) acc[i][j] = (f32x4){0.f, 0.f, 0.f, 0.f};

    uint4 u0 = *(const uint4*)gp;
    uint4 u1 = *(const uint4*)(gp + 256);
    gp += 32 * 256;

    for (int it = 0; it < 32; it++) {
        // transpose-write: pack (token 2q, 2q+1) per col, swizzled slot
        const unsigned int* w0 = (const unsigned int*)&u0;
        const unsigned int* w1 = (const unsigned int*)&u1;
#pragma unroll
        for (int ii = 0; ii < 8; ii++) {
            unsigned int lo = (w0[ii >> 1] >> (16 * (ii & 1))) & 0xFFFFu;
            unsigned int hi = (w1[ii >> 1] >> (16 * (ii & 1))) & 0xFFFFu;
            const int col = pi + ii;
            const int s2 = ((col >> 3) ^ col) & 3;
            const int s4 = ((col >> 2) ^ (col >> 5)) & 1;
            dst[col * 32 + (ptq ^ (s2 << 2) ^ (s4 << 4))] = lo | (hi << 16);
        }
        __syncthreads();
        if (it < 31) {  // prefetch next K-chunk; latency hides under MFMA phase
            u0 = *(const uint4*)gp;
            u1 = *(const uint4*)(gp + 256);
            gp += 32 * 256;
        }
        bf16x8 af[4], bfr[2];
#pragma unroll
        for (int i = 0; i < 4; i++) {
            const int col = wr + i * 16 + fr;
            const int s2 = ((col >> 3) ^ col) & 3;
            const int s4 = ((col >> 2) ^ (col >> 5)) & 1;
            af[i] = *(const bf16x8*)&As[col * 64 + (fkb ^ s2 ^ (s4 << 2)) * 8];
        }
#pragma unroll
        for (int j = 0; j < 2; j++) {
            const int col = wc + j * 16 + fr;
            const int s2 = ((col >> 3) ^ col) & 3;
            const int s4 = ((col >> 2) ^ (col >> 5)) & 1;
            bfr[j] = *(const bf16x8*)&Bs2[col * 64 + (fkb ^ s2 ^ (s4 << 2)) * 8];
        }
#pragma unroll
        for (int i = 0; i < 4; i++)
#pragma unroll
            for (int j = 0; j < 2; j++)
                acc[i][j] = __builtin_amdgcn_mfma_f32_16x16x32_bf16(
                    af[i], bfr[j], acc[i][j], 0, 0, 0);
        __syncthreads();
    }

    float* P = pbuf + (size_t)((layer << 5) + zc) * 65536;
    const int r0 = fkb * 4;
#pragma unroll
    for (int mi = 0; mi < 4; mi++)
#pragma unroll
        for (int ni = 0; ni < 2; ni++) {
            f32x4 c = acc[mi][ni];
#pragma unroll
            for (int r = 0; r < 4; r++)
                P[(size_t)(i0 + wr + mi * 16 + r0 + r) * 256 +
                  (j0 + wc + ni * 16 + fr)] = c[r];
        }
}

// ---------------------------------------------------------------------------
// gradstep: reduce pbuf (32 chunks) -> g; surprises; AdamW for W and b.
// blocks 0..511: weights (256 threads each). block 512: biases.
// ---------------------------------------------------------------------------
__global__ __launch_bounds__(256) void gradstep_k(
    const float* __restrict__ pbuf, const float* __restrict__ Ws,
    const float* __restrict__ bs, const float* __restrict__ accB,
    unsigned short* __restrict__ nWt, float* __restrict__ nb,
    float* __restrict__ outSW, float* __restrict__ outSb) {
    const int bi = blockIdx.x;
    if (bi < 512) {
        const int idx = bi * 256 + threadIdx.x;  // 0..131071
        const int layer = idx >> 16, rc = idx & 65535;
        const float* p = pbuf + (size_t)layer * 32 * 65536 + rc;
        float g = 0.f;
#pragma unroll 8
        for (int c = 0; c < 32; c++) g += p[(size_t)c * 65536];
        outSW[idx] = -g;
        float nw = Ws[idx] * (1.f - LRc * WDc) - LRc * g / (fabsf(g) + EPSc);
        const int l = idx >> 16, k = (idx >> 8) & 255, n = idx & 255;
        nWt[(size_t)l * 65536 + n * 256 + k] = f2b(nw);
    } else {
        for (int i = threadIdx.x; i < 512; i += 256) {
            float g = accB[i];
            outSb[i] = -g;
            nb[i] = bs[i] * (1.f - LRc * WDc) - LRc * g / (fabsf(g) + EPSc);
        }
    }
}

// ---------------------------------------------------------------------------
// prep_w: blocks 0..1535 -> weight transpose+cvt (z=0..4) / cvt (z=5)
//         block 1536     -> zero accB[512]
// ---------------------------------------------------------------------------
__global__ __launch_bounds__(256) void prep_w_k(
    const float* __restrict__ Wk, const float* __restrict__ Wq,
    const float* __restrict__ Wv, const float* __restrict__ Ws,
    unsigned short* __restrict__ wt, float* __restrict__ accB) {
    const int bi = blockIdx.x;
    if (bi < 1536) {
        const int z = bi >> 8;
        const int idx = (bi & 255) * 256 + threadIdx.x;  // 0..65535
        const float* src = z == 0 ? Wk : z == 1 ? Wq : z == 2 ? Wv
                         : z == 3 ? Ws : Ws + 65536;
        unsigned short* dst = wt + (size_t)z * 65536;
        float v = src[idx];
        if (z == 5)
            dst[idx] = f2b(v);
        else
            dst[(idx & 255) * 256 + (idx >> 8)] = f2b(v);
    } else {
        accB[threadIdx.x] = 0.f;
        accB[threadIdx.x + 256] = 0.f;
    }
}

extern "C" void kernel_launch(void* const* d_in, const int* in_sizes, int n_in,
                              void* d_out, int out_size, void* d_ws,
                              size_t ws_size, hipStream_t stream) {
    const float* x = (const float*)d_in[0];
    const float* Wk = (const float*)d_in[1];
    const float* Wq = (const float*)d_in[2];
    const float* Wv = (const float*)d_in[3];
    const float* Wlr = (const float*)d_in[4];
    const float* blr = (const float*)d_in[5];
    const float* Ws = (const float*)d_in[6];
    const float* bs = (const float*)d_in[7];

    unsigned short* S = (unsigned short*)d_ws;
    unsigned short* xb = S + 0 * NM;  // r1b scratch (retrieval intermediate)
    unsigned short* Kb = S + 1 * NM;
    unsigned short* Qb = S + 2 * NM;
    unsigned short* Vb = S + 3 * NM;
    unsigned short* z0b = S + 4 * NM;
    unsigned short* h1b = S + 5 * NM;
    unsigned short* dz1b = S + 6 * NM;
    unsigned short* dh2b = S + 7 * NM;
    unsigned short* dz0b = S + 8 * NM;
    float* pbuf = (float*)(S + 9 * NM);  // 16 MB (slot 9): 2 layers x 32 chunks
    unsigned short* r1b = xb;

    unsigned short* wt = S + 11 * NM;
    unsigned short* W0t = wt + 3 * 65536;
    unsigned short* W1t = wt + 4 * 65536;
    unsigned short* W1b = wt + 5 * 65536;
    unsigned short* nW0t = wt + 6 * 65536;
    unsigned short* nW1t = wt + 7 * 65536;
    float* ft = (float*)(wt + 8 * 65536);
    float* alr = ft;              // 32768
    float* accB = ft + 32768;     // 512
    float* nb = accB + 512;       // 512

    float* out_ret = (float*)d_out;
    float* out_sW = out_ret + NM;
    float* out_sb = out_sW + 131072;

    dim3 blk5(512);
    dim3 blk(256);

    // prep: weight transpose/cvt + zero accB (x handled inside wgemm3_k)
    prep_w_k<<<1537, blk, 0, stream>>>(Wk, Wq, Wv, Ws, wt, accB);

    // projections K,Q,V (+ x->bf16 conversion + alr), z-loop inside block
    wgemm3_k<<<512, blk5, 0, stream>>>(x, Wlr, blr, wt, Kb, Qb, Vb, alr);

    // fwd layer 0: h1 = K + silu(K@W0 + b0); saves z0
    wgemm_k<1><<<512, blk5, 0, stream>>>(Kb, W0t, bs, nullptr, nullptr,
                                         nullptr, nullptr, nullptr, h1b,
                                         nullptr, z0b, nullptr);

    // fwd layer 1 + bwd elementwise: dz1, dh2 (+ colsum dz1 -> accB[256..])
    wgemm_k<5><<<512, blk5, 0, stream>>>(h1b, W1t, bs + 256, nullptr,
                                         nullptr, Vb, alr, accB + 256,
                                         dz1b, nullptr, nullptr, dh2b);

    // bwd layer 0: dz0 = (dz1@W1^T + dh2) * dsilu(z0) (+ colsum -> accB[0..])
    wgemm_k<2><<<512, blk5, 0, stream>>>(dz1b, W1b, nullptr, dh2b, z0b,
                                         nullptr, nullptr, accB, dz0b,
                                         nullptr, nullptr, nullptr);

    // weight grads: swizzled transpose-on-load split-K partials
    rgemm_k<<<dim3(2, 2, 64), blk5, 0, stream>>>(Kb, h1b, dz0b, dz1b, pbuf);

    // reduce + surprises + AdamW (W and b) in one dispatch
    gradstep_k<<<513, blk, 0, stream>>>(pbuf, Ws, bs, accB, nW0t, nb, out_sW,
                                        out_sb);

    // retrieved with new weights (two tall passes)
    wgemm_k<3><<<512, blk5, 0, stream>>>(Qb, nW0t, nb, nullptr, nullptr,
                                         nullptr, nullptr, nullptr, r1b,
                                         nullptr, nullptr, nullptr);
    wgemm_k<4><<<512, blk5, 0, stream>>>(r1b, nW1t, nb + 256, nullptr,
                                         nullptr, nullptr, nullptr, nullptr,
                                         nullptr, out_ret, nullptr, nullptr);
}